// Round 5
// baseline (524.013 us; speedup 1.0000x reference)
//
#include <hip/hip_runtime.h>
#include <stdint.h>

// Block-sparse linear: out[8192,4096] = x @ W^T + bias, W BSR 64x64 blocks.
// R8: B off LDS. Counter-derived facts: (1) we are REGISTER-capped at ~2
// WG/CU (56 VGPR + 64 AGPR acc ~= 120 unified -> 4 waves/SIMD), so LDS up
// to 80KB is free; (2) LDS pipe is the top consumer (~70% busy: 128KB reads
// + 48KB writes per WG-col-step), and B accounts for 64KB reads + 16KB
// writes of that while being tiny (8KB/block) and L2-resident (W=16MB <
// 32MB L2). So: load B fragments per-wave directly from global (L1-shared
// across the 4 same-wn waves), LDS holds A only: 2 x 32KB dbuf = 64KB,
// BK back to 64 (R3-size MFMA clusters), ONE __syncthreads per col-step
// (32 barriers total vs R7's 64). A staging/read = R3's verified
// 0-conflict 128B-row swizzle, unchanged. Pipeline: stage(t+1) issued
// before compute(t) (proven R7 invariant, one barrier/step).

#define BATCH   8192
#define IN_F    4096
#define OUT_F   4096
#define BS      64
#define NROW    64
#define NNZB    2048
#define BM      256                        // batch rows per workgroup
#define LDS_A_BYTES (BM * BS * 2)          // 32768 (A only, BK=64)
#define BUF_BYTES   LDS_A_BYTES
#define NBUF    2                          // 65536 B total (<=80KB 2-WG cap)

typedef float f32x4 __attribute__((ext_vector_type(4)));
typedef short s16x8 __attribute__((ext_vector_type(8)));   // 8 x bf16

__device__ __forceinline__ void async_copy16(const void* g, void* l) {
  // global -> LDS direct DMA, 16 B/lane. LDS dest = wave base + lane*16.
  __builtin_amdgcn_global_load_lds(
      (__attribute__((address_space(1))) void*)g,
      (__attribute__((address_space(3))) void*)l, 16, 0, 0);
}

__device__ __forceinline__ unsigned short f32_to_bf16(float f) {
  union { float f; uint32_t u; } v; v.f = f;
  return (unsigned short)((v.u + 0x7FFFu + ((v.u >> 16) & 1u)) >> 16);
}

// Single fused cvt for x and values (one launch instead of two).
__global__ void cvt_kernel(const float4* __restrict__ xin,
                           const float4* __restrict__ win,
                           ushort4* __restrict__ xout,
                           ushort4* __restrict__ wout, int nx4, int ntot4) {
  int i = blockIdx.x * blockDim.x + threadIdx.x;
  if (i >= ntot4) return;
  const float4* src; ushort4* dst; int j;
  if (i < nx4) { src = xin; dst = xout; j = i; }
  else         { src = win; dst = wout; j = i - nx4; }
  float4 v = src[j];
  ushort4 o;
  o.x = f32_to_bf16(v.x); o.y = f32_to_bf16(v.y);
  o.z = f32_to_bf16(v.z); o.w = f32_to_bf16(v.w);
  dst[j] = o;
}

// GEMM: grid (NROW/2=32 pairs, BATCH/BM=32), block 512 = 8 waves.
// Pair p -> rows rA=(p>>1)*4+(p&1), rB=rA+2 (same parity -> same cols in
// this dataset; merge table handles arbitrary overlap). Wave w: wm=w&3
// (64-row m-quarter), wn=w>>2 (which block-row of the pair).
__global__ __launch_bounds__(512) void bsr_gemm_pair_kernel(
    const unsigned short* __restrict__ xb,   // bf16 [BATCH][IN_F]
    const unsigned short* __restrict__ wb,   // bf16 [NNZB][64][64] ([n][k])
    const float* __restrict__ bias,
    const int* __restrict__ crow,
    const int* __restrict__ cols,
    float* __restrict__ out) {
  __shared__ alignas(16) char smem[NBUF * BUF_BYTES];

  const int tid = threadIdx.x;
  const int w   = tid >> 6;        // wave 0..7
  const int l   = tid & 63;        // lane
  const int wm  = w & 3;           // m-quarter
  const int wn  = w >> 2;          // block-row within pair (0=A,1=B)
  const int p   = blockIdx.x;
  const int rA  = ((p >> 1) << 2) + (p & 1);
  const int rB  = rA + 2;
  const int m0  = blockIdx.y * BM;

  const int startA = crow[rA], endA = crow[rA + 1];
  const int startB = crow[rB], endB = crow[rB + 1];

  const int lr = l & 15;           // MFMA m/n index within 16
  const int q  = l >> 4;           // quad 0..3 (k-chunk owner)

  // Preload both sorted col lists into lane registers (<=64 entries each).
  int cvA = (startA + l < endA) ? cols[startA + l] : 0;
  int cvB = (startB + l < endB) ? cols[startB + l] : 0;

  // ---- Precompute merged step table into lane-indexed registers. ----
  // Lane t holds step t: col (myc) and packed {sA, sB, hasA, hasB} (mypk).
  // sA/sB CLAMPED valid indices -> staging/loads are branchless-safe.
  int myc = 0, mypk = 0;
  int nt = 0;
  {
    int ia = startA, ib = startB;
    const int clA = (endA > startA) ? endA - 1 : 0;
    const int clB = (endB > startB) ? endB - 1 : 0;
    while ((ia < endA) || (ib < endB)) {
      const int ca = (ia < endA) ? __shfl(cvA, ia - startA) : 0x7fffffff;
      const int cb = (ib < endB) ? __shfl(cvB, ib - startB) : 0x7fffffff;
      const int c  = min(ca, cb);
      const int hA = (ca == c);
      const int hB = (cb == c);
      const int sA = hA ? ia : clA;
      const int sB = hB ? ib : clB;
      if (nt == l) { myc = c; mypk = sA | (sB << 12) | (hA << 24) | (hB << 25); }
      ia += hA; ib += hB; ++nt;
    }
  }

  f32x4 acc[4][4];
#pragma unroll
  for (int mi = 0; mi < 4; ++mi)
#pragma unroll
    for (int ni = 0; ni < 4; ++ni) {
      f32x4 z = {0.f, 0.f, 0.f, 0.f};
      acc[mi][ni] = z;
    }

  // A staging lane roles (512 threads, 128B rows — R3's verified layout):
  // row = tid>>3 (0..63 per issue), slot = tid&7, global 16B chunk =
  // slot ^ (row&7). 4 issues of 8KB cover 256 rows x 128B.
  const int srow = tid >> 3;
  const int sswz = ((tid & 7) ^ (srow & 7)) << 3;              // elements
  const unsigned short* agbase =
      xb + (size_t)(m0 + srow) * IN_F + sswz;                  // + c*64
  char* const alds = smem + tid * 16;                          // + buf*32768

  // Issue the 4 A global_load_lds for step t into buffer buf.
  auto stage = [&](int t, int buf) {
    const int c = __shfl(myc, t);
    char* const al = alds + buf * BUF_BYTES;
    const unsigned short* ag = agbase + (size_t)c * BS;
#pragma unroll
    for (int it = 0; it < 4; ++it)                 // A: 256 rows x 128 B
      async_copy16(ag + (size_t)(it * 64) * IN_F, al + it * 8192);
  };

  // Per-lane B fragment offset (elements): row lr, k-quad q.
  const int boff = (lr << 6) + (q << 3);

  // ---- Pipelined K-loop: BK=64, ONE __syncthreads per col-step. ----
  // Invariant (proven in R7): at top of iter t, cur=t&1; stage(t+1) writes
  // buf[cur^1]; compute(t) reads buf[cur]; barrier at end of iter t ensures
  // compute reads done AND stage(t+1) landed before iter t+1.
  if (nt > 0) stage(0, 0);
  __syncthreads();
  int cur = 0;
  for (int t = 0; t < nt; ++t) {
    if (t + 1 < nt) stage(t + 1, cur ^ 1);

    const int pk = __shfl(mypk, t);
    const char* const cbase = smem + cur * BUF_BYTES;
    if ((pk >> (24 + wn)) & 1) {                   // this wave's row has col c
      const int sblk = wn ? ((pk >> 12) & 0xfff) : (pk & 0xfff);
      const unsigned short* wbase = wb + ((size_t)sblk << 12) + boff;
      __builtin_amdgcn_s_setprio(1);
#pragma unroll
      for (int ks = 0; ks < 2; ++ks) {
        const int chunk = (((ks << 2) + q) ^ (l & 7)) << 4;    // bytes
        s16x8 af[4], bf[4];
#pragma unroll
        for (int mi = 0; mi < 4; ++mi)   // A[m][k] from LDS, swizzled chunk
          af[mi] = *(const s16x8*)(cbase +
                     ((wm << 6) + (mi << 4) + lr) * 128 + chunk);
#pragma unroll
        for (int ni = 0; ni < 4; ++ni)   // B^T[n][k] direct from global (L1/L2-hot)
          bf[ni] = *(const s16x8*)(wbase + (ni << 10) + (ks << 5));
#pragma unroll
        for (int mi = 0; mi < 4; ++mi)
#pragma unroll
          for (int ni = 0; ni < 4; ++ni)
            acc[mi][ni] = __builtin_amdgcn_mfma_f32_16x16x32_bf16(
                af[mi], bf[ni], acc[mi][ni], 0, 0, 0);
      }
      __builtin_amdgcn_s_setprio(0);
    }
    __syncthreads();
    cur ^= 1;
  }

  // Epilogue: C/D layout col=lr, row=q*4+reg. Add bias, store fp32.
  const int rW = wn ? rB : rA;
  const int colg = (rW << 6) + lr;
#pragma unroll
  for (int ni = 0; ni < 4; ++ni) {
    const float bv = bias[colg + (ni << 4)];
#pragma unroll
    for (int mi = 0; mi < 4; ++mi) {
      float* op = out +
          (size_t)(m0 + (wm << 6) + (mi << 4) + (q << 2)) * OUT_F +
          colg + (ni << 4);
#pragma unroll
      for (int e = 0; e < 4; ++e)
        op[(size_t)e * OUT_F] = acc[mi][ni][e] + bv;
    }
  }
}

// Safety net if ws_size < 84 MB: naive fp32, one thread per output element.
__global__ void fallback_kernel(const float* __restrict__ x,
                                const float* __restrict__ vals,
                                const float* __restrict__ bias,
                                const int* __restrict__ crow,
                                const int* __restrict__ cols,
                                float* __restrict__ out) {
  int idx = blockIdx.x * 256 + threadIdx.x;
  int m = idx >> 12;
  int n = idx & 4095;
  int r = n >> 6, nl = n & 63;
  float s = 0.f;
  int e = crow[r + 1];
  for (int i = crow[r]; i < e; ++i) {
    const float* xp = x + (size_t)m * IN_F + cols[i] * 64;
    const float* wp = vals + ((size_t)i << 12) + nl * 64;
    for (int k = 0; k < 64; ++k) s += xp[k] * wp[k];
  }
  out[idx] = s + bias[n];
}

extern "C" void kernel_launch(void* const* d_in, const int* in_sizes, int n_in,
                              void* d_out, int out_size, void* d_ws,
                              size_t ws_size, hipStream_t stream) {
  const float* x    = (const float*)d_in[0];
  const float* vals = (const float*)d_in[1];
  const float* bias = (const float*)d_in[2];
  const int*   crow = (const int*)d_in[3];
  const int*   cols = (const int*)d_in[4];
  float* out = (float*)d_out;

  const size_t x_elems = (size_t)BATCH * IN_F;       // 33.5M
  const size_t w_elems = (size_t)NNZB * BS * BS;     // 8.4M
  const size_t need = (x_elems + w_elems) * 2;       // bf16 bytes, ~84 MB

  if (ws_size >= need) {
    unsigned short* xb = (unsigned short*)d_ws;
    unsigned short* wbp = xb + x_elems;
    const int nx4 = (int)(x_elems / 4);
    const int ntot4 = (int)((x_elems + w_elems) / 4);
    cvt_kernel<<<(ntot4 + 255) / 256, 256, 0, stream>>>(
        (const float4*)x, (const float4*)vals,
        (ushort4*)xb, (ushort4*)wbp, nx4, ntot4);
    dim3 grid(NROW / 2, BATCH / BM);  // pair-fast: same x-slab hot in L2
    bsr_gemm_pair_kernel<<<grid, 512, 0, stream>>>(xb, wbp, bias, crow, cols,
                                                   out);
  } else {
    fallback_kernel<<<(BATCH * OUT_F) / 256, 256, 0, stream>>>(
        x, vals, bias, crow, cols, out);
  }
}

// Round 6
// 378.046 us; speedup vs baseline: 1.3861x; 1.3861x over previous
//
#include <hip/hip_runtime.h>
#include <stdint.h>

// Block-sparse linear: out[8192,4096] = x @ W^T + bias, W BSR 64x64 blocks.
// R9: bigger wave tiles to cut LDS-read amplification. Scoreboard: R3
// (single 48KB buffer, stage->sync->compute->sync, BK=64, 8 waves of 64x64
// tiles) = 148us best; R5-R8 schedule experiments all lost. R8's failure:
// vmcnt is an in-order FIFO, so per-step B global-loads forced a drain of
// the younger stage(t+1) loads -> compute serialized on next-step staging.
// Model: per WG-step MFMA=1240cy, LDS=~1920cy (reads 128KB: A x2, B x4
// amplification from 64x64 wave tiles). Fix: 4 waves x 128x64 tiles (same
// 256x128 WG output, same 48KB LDS, same staging bytes) -> reads 96KB/step,
// LDS ~1530cy, balanced with MFMA. acc=128 VGPR/wave -> ~200 total -> 2
// waves/SIMD = 2 WGs/CU co-resident (the TLP R3 proved essential) with
// 96KB LDS. __launch_bounds__(256,2) pins it. R3's verified 0-conflict
// swizzles kept byte-identical; R3's schedule kept exactly.

#define BATCH   8192
#define IN_F    4096
#define OUT_F   4096
#define BS      64
#define NROW    64
#define NNZB    2048
#define BM      256                        // batch rows per workgroup
#define LDS_A_BYTES (BM * BS * 2)          // 32768
#define LDS_B_BYTES (2 * BS * BS * 2)      // 16384 (two W blocks)

typedef float f32x4 __attribute__((ext_vector_type(4)));
typedef short s16x8 __attribute__((ext_vector_type(8)));   // 8 x bf16

__device__ __forceinline__ void async_copy16(const void* g, void* l) {
  // global -> LDS direct DMA, 16 B/lane. LDS dest = wave base + lane*16.
  __builtin_amdgcn_global_load_lds(
      (__attribute__((address_space(1))) void*)g,
      (__attribute__((address_space(3))) void*)l, 16, 0, 0);
}

__device__ __forceinline__ unsigned short f32_to_bf16(float f) {
  union { float f; uint32_t u; } v; v.f = f;
  return (unsigned short)((v.u + 0x7FFFu + ((v.u >> 16) & 1u)) >> 16);
}

// Single fused cvt for x and values (one launch instead of two).
__global__ void cvt_kernel(const float4* __restrict__ xin,
                           const float4* __restrict__ win,
                           ushort4* __restrict__ xout,
                           ushort4* __restrict__ wout, int nx4, int ntot4) {
  int i = blockIdx.x * blockDim.x + threadIdx.x;
  if (i >= ntot4) return;
  const float4* src; ushort4* dst; int j;
  if (i < nx4) { src = xin; dst = xout; j = i; }
  else         { src = win; dst = wout; j = i - nx4; }
  float4 v = src[j];
  ushort4 o;
  o.x = f32_to_bf16(v.x); o.y = f32_to_bf16(v.y);
  o.z = f32_to_bf16(v.z); o.w = f32_to_bf16(v.w);
  dst[j] = o;
}

// GEMM: grid (NROW/2=32 pairs, BATCH/BM=32), block 256 = 4 waves.
// Pair p -> rows rA=(p>>1)*4+(p&1), rB=rA+2 (same parity -> same cols in
// this dataset; merge table handles arbitrary overlap).
// Wave w: wm=w&1 (128-row m-half), wn=w>>1 (block-row of the pair).
// Per wave output tile: 128 x 64 (acc[8][4] f32x4).
__global__ __launch_bounds__(256, 2) void bsr_gemm_pair_kernel(
    const unsigned short* __restrict__ xb,   // bf16 [BATCH][IN_F]
    const unsigned short* __restrict__ wb,   // bf16 [NNZB][64][64] ([n][k])
    const float* __restrict__ bias,
    const int* __restrict__ crow,
    const int* __restrict__ cols,
    float* __restrict__ out) {
  __shared__ alignas(16) char smem[LDS_A_BYTES + LDS_B_BYTES];

  const int tid = threadIdx.x;
  const int w   = tid >> 6;        // wave 0..3
  const int l   = tid & 63;        // lane
  const int wm  = w & 1;           // m-half (128 rows)
  const int wn  = w >> 1;          // block-row within pair (0=A,1=B)
  const int p   = blockIdx.x;
  const int rA  = ((p >> 1) << 2) + (p & 1);
  const int rB  = rA + 2;
  const int m0  = blockIdx.y * BM;

  const int startA = crow[rA], endA = crow[rA + 1];
  const int startB = crow[rB], endB = crow[rB + 1];

  const int lr = l & 15;           // MFMA m/n index within 16
  const int q  = l >> 4;           // quad 0..3 (k-chunk owner)

  // Preload both sorted col lists into lane registers (<=64 entries each).
  int cvA = (startA + l < endA) ? cols[startA + l] : 0;
  int cvB = (startB + l < endB) ? cols[startB + l] : 0;

  // ---- Precompute merged step table into lane-indexed registers. ----
  // Lane t holds step t: col (myc) and packed {sA, sB, hasA, hasB} (mypk).
  // sA/sB CLAMPED valid indices -> staging is branchless/uniform.
  int myc = 0, mypk = 0;
  int nt = 0;
  {
    int ia = startA, ib = startB;
    const int clA = (endA > startA) ? endA - 1 : 0;
    const int clB = (endB > startB) ? endB - 1 : 0;
    while ((ia < endA) || (ib < endB)) {
      const int ca = (ia < endA) ? __shfl(cvA, ia - startA) : 0x7fffffff;
      const int cb = (ib < endB) ? __shfl(cvB, ib - startB) : 0x7fffffff;
      const int c  = min(ca, cb);
      const int hA = (ca == c);
      const int hB = (cb == c);
      const int sA = hA ? ia : clA;
      const int sB = hB ? ib : clB;
      if (nt == l) { myc = c; mypk = sA | (sB << 12) | (hA << 24) | (hB << 25); }
      ia += hA; ib += hB; ++nt;
    }
  }

  f32x4 acc[8][4];
#pragma unroll
  for (int mi = 0; mi < 8; ++mi)
#pragma unroll
    for (int ni = 0; ni < 4; ++ni) {
      f32x4 z = {0.f, 0.f, 0.f, 0.f};
      acc[mi][ni] = z;
    }

  // Staging lane roles (256 threads, 128B rows — R3's verified swizzle):
  // per issue, row = tid>>3 (0..31), slot = tid&7, global 16B chunk =
  // slot ^ (row&7). Row offsets of +32 per issue keep (row&7) invariant.
  // A: 8 issues x 4KB = 32KB; B: 2 issues per block x 2 blocks = 16KB.
  const int srow = tid >> 3;
  const int sswz = ((tid & 7) ^ (srow & 7)) << 3;              // elements
  const unsigned short* agbase =
      xb + (size_t)(m0 + srow) * IN_F + sswz;                  // + c*64
  const int bgoff = (srow << 6) + sswz;                        // elements
  char* const alds = smem + tid * 16;
  char* const blds = smem + LDS_A_BYTES + tid * 16;

  // Issue the 12 global_load_lds for step t (single buffer, R3 schedule).
  auto stage = [&](int t) {
    const int pk = __shfl(mypk, t);
    const int c  = __shfl(myc, t);
    const int sA = pk & 0xfff;
    const int sB = (pk >> 12) & 0xfff;
    const unsigned short* ag = agbase + (size_t)c * BS;
#pragma unroll
    for (int it = 0; it < 8; ++it)                 // A: 256 rows x 128 B
      async_copy16(ag + (size_t)(it * 32) * IN_F, alds + it * 4096);
    const unsigned short* w0 = wb + ((size_t)sA << 12) + bgoff;
    async_copy16(w0, blds);                        // rA rows 0..31
    async_copy16(w0 + 2048, blds + 4096);          // rA rows 32..63
    const unsigned short* w1 = wb + ((size_t)sB << 12) + bgoff;
    async_copy16(w1, blds + 8192);                 // rB rows 0..31
    async_copy16(w1 + 2048, blds + 12288);         // rB rows 32..63
  };

  // ---- K-loop: R3's proven schedule (sync; stage; sync; compute). ----
  for (int t = 0; t < nt; ++t) {
    __syncthreads();   // previous compute done before LDS overwrite
    stage(t);
    __syncthreads();   // drains vmcnt -> staged data visible

    const int pk = __shfl(mypk, t);
    if ((pk >> (24 + wn)) & 1) {                   // this wave's row has col c
      __builtin_amdgcn_s_setprio(1);
#pragma unroll
      for (int ks = 0; ks < 2; ++ks) {
        const int chunk = (((ks << 2) + q) ^ (l & 7)) << 4;    // bytes
        s16x8 af[8], bf[4];
#pragma unroll
        for (int mi = 0; mi < 8; ++mi)   // A[m][k], swizzled chunk
          af[mi] = *(const s16x8*)(smem +
                     ((wm << 7) + (mi << 4) + lr) * 128 + chunk);
#pragma unroll
        for (int ni = 0; ni < 4; ++ni)   // B^T[n][k], region wn
          bf[ni] = *(const s16x8*)(smem + LDS_A_BYTES + (wn << 13) +
                     ((ni << 4) + lr) * 128 + chunk);
#pragma unroll
        for (int mi = 0; mi < 8; ++mi)
#pragma unroll
          for (int ni = 0; ni < 4; ++ni)
            acc[mi][ni] = __builtin_amdgcn_mfma_f32_16x16x32_bf16(
                af[mi], bf[ni], acc[mi][ni], 0, 0, 0);
      }
      __builtin_amdgcn_s_setprio(0);
    }
  }

  // Epilogue: C/D layout col=lr, row=q*4+reg. Add bias, store fp32.
  const int rW = wn ? rB : rA;
  const int colg = (rW << 6) + lr;
#pragma unroll
  for (int ni = 0; ni < 4; ++ni) {
    const float bv = bias[colg + (ni << 4)];
#pragma unroll
    for (int mi = 0; mi < 8; ++mi) {
      float* op = out +
          (size_t)(m0 + (wm << 7) + (mi << 4) + (q << 2)) * OUT_F +
          colg + (ni << 4);
#pragma unroll
      for (int e = 0; e < 4; ++e)
        op[(size_t)e * OUT_F] = acc[mi][ni][e] + bv;
    }
  }
}

// Safety net if ws_size < 84 MB: naive fp32, one thread per output element.
__global__ void fallback_kernel(const float* __restrict__ x,
                                const float* __restrict__ vals,
                                const float* __restrict__ bias,
                                const int* __restrict__ crow,
                                const int* __restrict__ cols,
                                float* __restrict__ out) {
  int idx = blockIdx.x * 256 + threadIdx.x;
  int m = idx >> 12;
  int n = idx & 4095;
  int r = n >> 6, nl = n & 63;
  float s = 0.f;
  int e = crow[r + 1];
  for (int i = crow[r]; i < e; ++i) {
    const float* xp = x + (size_t)m * IN_F + cols[i] * 64;
    const float* wp = vals + ((size_t)i << 12) + nl * 64;
    for (int k = 0; k < 64; ++k) s += xp[k] * wp[k];
  }
  out[idx] = s + bias[n];
}

extern "C" void kernel_launch(void* const* d_in, const int* in_sizes, int n_in,
                              void* d_out, int out_size, void* d_ws,
                              size_t ws_size, hipStream_t stream) {
  const float* x    = (const float*)d_in[0];
  const float* vals = (const float*)d_in[1];
  const float* bias = (const float*)d_in[2];
  const int*   crow = (const int*)d_in[3];
  const int*   cols = (const int*)d_in[4];
  float* out = (float*)d_out;

  const size_t x_elems = (size_t)BATCH * IN_F;       // 33.5M
  const size_t w_elems = (size_t)NNZB * BS * BS;     // 8.4M
  const size_t need = (x_elems + w_elems) * 2;       // bf16 bytes, ~84 MB

  if (ws_size >= need) {
    unsigned short* xb = (unsigned short*)d_ws;
    unsigned short* wbp = xb + x_elems;
    const int nx4 = (int)(x_elems / 4);
    const int ntot4 = (int)((x_elems + w_elems) / 4);
    cvt_kernel<<<(ntot4 + 255) / 256, 256, 0, stream>>>(
        (const float4*)x, (const float4*)vals,
        (ushort4*)xb, (ushort4*)wbp, nx4, ntot4);
    dim3 grid(NROW / 2, BATCH / BM);  // pair-fast: same x-slab hot in L2
    bsr_gemm_pair_kernel<<<grid, 256, 0, stream>>>(xb, wbp, bias, crow, cols,
                                                   out);
  } else {
    fallback_kernel<<<(BATCH * OUT_F) / 256, 256, 0, stream>>>(
        x, vals, bias, crow, cols, out);
  }
}